// Round 2
// baseline (435.514 us; speedup 1.0000x reference)
//
#include <hip/hip_runtime.h>

// IndRNN (recurrent-only): h_t = relu(x_t + w_hh * h_{t-1})
// x: [T=2048, B=64, H=512] fp32, w: [H], out: [T, B, H] fp32.
//
// One thread per (b,h) chain (32768 threads = 512 waves, 2 waves/CU).
// Latency hiding is pure ILP: cp.async-style pipeline via
// global_load_lds (4 B/lane -> one 256 B x-row per wave per t into an
// LDS ring slot) + MANUAL s_waitcnt vmcnt(N). The compiler does not
// model the DMA->LDS dependency, so our waits are the only vmcnt's:
// full control of prefetch depth (PD=24 steps in flight).
//
// Wait accounting (window model): each 8-step group issues exactly
// 8 global stores + 8 DMA loads (16 vmcnt ops) between waitcnt
// barriers. Loads for group g were issued 3 windows back -> at least
// 2 full windows (32 ops) follow them -> vmcnt(32) guarantees
// completion, independent of scheduling order inside a window.

#define T_SEQ 2048
#define BATCH 64
#define HIDDEN 512

constexpr int STRIDE = BATCH * HIDDEN;  // 32768 elems between t-steps
constexpr int NCHAIN = BATCH * HIDDEN;
constexpr int RING = 32;                // LDS ring slots (== chunk size)
constexpr int PD = 24;                  // prefetch distance in t-steps
constexpr int GRP = 8;                  // t-steps per wait-group

#define GLOBAL_AS __attribute__((address_space(1)))
#define LDS_AS __attribute__((address_space(3)))

// s_waitcnt imm (gfx9 enc): vmcnt bits [3:0]+[15:14], expcnt [6:4]=7,
// lgkmcnt [11:8]=0xF (i.e. don't constrain exp/lgkm).
constexpr unsigned vm(unsigned n) {
  return ((n & 0x30u) << 10) | 0xF70u | (n & 0xFu);
}

template <unsigned WAITN, bool LOAD>
__device__ __forceinline__ void group(int j0, int t0, float& hv,
                                      const float wh,
                                      const float* __restrict__ xp,
                                      float* __restrict__ op,
                                      float* ring, int lane) {
  __builtin_amdgcn_s_waitcnt(vm(WAITN));
  float v[GRP];
#pragma unroll
  for (int i = 0; i < GRP; ++i)
    v[i] = ring[((j0 + i) & (RING - 1)) * 64 + lane];  // ds_read_b32
#pragma unroll
  for (int i = 0; i < GRP; ++i) {
    hv = fmaxf(0.0f, fmaf(wh, hv, v[i]));
    __builtin_nontemporal_store(hv, op + (size_t)(t0 + i) * STRIDE);
  }
  if (LOAD) {
#pragma unroll
    for (int i = 0; i < GRP; ++i) {
      const int t = t0 + PD + i;
      const int slot = (j0 + PD + i) & (RING - 1);
      __builtin_amdgcn_global_load_lds(
          (const GLOBAL_AS void*)(xp + (size_t)t * STRIDE),
          (LDS_AS void*)(&ring[slot * 64]), 4, 0, 0);
    }
  }
}

__global__ __launch_bounds__(64) void indrnn_kernel(
    const float* __restrict__ x, const float* __restrict__ w,
    float* __restrict__ out) {
  __shared__ float ring[RING * 64];  // 8 KB: 32 slots x 256 B
  const int lane = threadIdx.x;
  const int idx = blockIdx.x * 64 + lane;  // chain id = b*H + h
  const float wh = w[idx & (HIDDEN - 1)];
  const float* xp = x + idx;  // per-lane global pointer, +t*STRIDE per step
  float* op = out + idx;

  // Prologue: fill first PD slots (24 DMA loads, no stores yet).
#pragma unroll
  for (int j = 0; j < PD; ++j) {
    __builtin_amdgcn_global_load_lds(
        (const GLOBAL_AS void*)(xp + (size_t)j * STRIDE),
        (LDS_AS void*)(&ring[j * 64]), 4, 0, 0);
  }

  float hv = 0.0f;

  // Chunk 0 (peel): prologue loads have no interleaved stores.
  group<16, true>(0, 0, hv, wh, xp, op, ring, lane);
  group<24, true>(8, 8, hv, wh, xp, op, ring, lane);
  group<32, true>(16, 16, hv, wh, xp, op, ring, lane);
  group<32, true>(24, 24, hv, wh, xp, op, ring, lane);

#pragma unroll 1
  for (int c = 1; c < T_SEQ / RING - 1; ++c) {
    const int t0 = c * RING;
    group<32, true>(0, t0, hv, wh, xp, op, ring, lane);
    group<32, true>(8, t0 + 8, hv, wh, xp, op, ring, lane);
    group<32, true>(16, t0 + 16, hv, wh, xp, op, ring, lane);
    group<32, true>(24, t0 + 24, hv, wh, xp, op, ring, lane);
  }

  // Last chunk: only group 0 still has in-range prefetches
  // (t0+PD = 2040..2047); later groups issue no loads, waits taper.
  {
    const int t0 = T_SEQ - RING;  // 2016
    group<32, true>(0, t0, hv, wh, xp, op, ring, lane);
    group<32, false>(8, t0 + 8, hv, wh, xp, op, ring, lane);
    group<24, false>(16, t0 + 16, hv, wh, xp, op, ring, lane);
    group<16, false>(24, t0 + 24, hv, wh, xp, op, ring, lane);
  }
}

extern "C" void kernel_launch(void* const* d_in, const int* in_sizes, int n_in,
                              void* d_out, int out_size, void* d_ws,
                              size_t ws_size, hipStream_t stream) {
  const float* x = (const float*)d_in[0];
  const float* w = (const float*)d_in[1];
  float* out = (float*)d_out;
  indrnn_kernel<<<NCHAIN / 64, 64, 0, stream>>>(x, w, out);
}